// Round 1
// baseline (3008.792 us; speedup 1.0000x reference)
//
#include <hip/hip_runtime.h>
#include <math.h>
#include <stdint.h>

#define N_LEVELS 8
#define D 64
#define HALF_D 32
#define NUM_OUT 16
#define TBITS 19
#define TMASK ((1u << TBITS) - 1u)
#define BLK 128

struct ResArr { float r[N_LEVELS]; };

__device__ __forceinline__ float sin2pi(float t) {
    float f = t - floorf(t);             // range-reduce to [0,1) revolutions
    return __builtin_amdgcn_sinf(f);     // v_sin_f32: sin(2*pi*f)
}
__device__ __forceinline__ float cos2pi(float t) {
    float f = t - floorf(t);
    return __builtin_amdgcn_cosf(f);
}

__global__ __launch_bounds__(BLK) void ffb_kernel(
    const float* __restrict__ input,
    const float* __restrict__ W0,
    const float* __restrict__ b0,
    const float* __restrict__ Ws,
    const float* __restrict__ bs,
    const float* __restrict__ tables,
    const float* __restrict__ Gw,
    const float* __restrict__ Gb,
    const float* __restrict__ Bmat,
    const float* __restrict__ Wout,
    const float* __restrict__ bout,
    float* __restrict__ out,
    int npts, ResArr resarr)
{
    // h lives in LDS, transposed [channel][thread]: every access is
    // lane-consecutive -> conflict-free, and each thread touches only its
    // own column -> no __syncthreads needed anywhere.
    __shared__ float lds_h[D][BLK];

    const int tid = threadIdx.x;
    const int n = blockIdx.x * BLK + tid;
    if (n >= npts) return;

    // x = input / BOUND ; xn = clip((x+1)*0.5, 0, 1-1e-6)
    const float inv_unused = 0.f; (void)inv_unused;
    float x0 = input[(size_t)n * 3 + 0] / 1.5f;
    float x1 = input[(size_t)n * 3 + 1] / 1.5f;
    float x2 = input[(size_t)n * 3 + 2] / 1.5f;
    const float hi = (float)(1.0 - 1e-6);
    float xn0 = fminf(fmaxf((x0 + 1.0f) * 0.5f, 0.0f), hi);
    float xn1 = fminf(fmaxf((x1 + 1.0f) * 0.5f, 0.0f), hi);
    float xn2 = fminf(fmaxf((x2 + 1.0f) * 0.5f, 0.0f), hi);

    float outacc[NUM_OUT];
#pragma unroll
    for (int o = 0; o < NUM_OUT; ++o) outacc[o] = 0.0f;

    for (int lev = 0; lev < N_LEVELS; ++lev) {
        // ---------- matvec: nh = h @ W + b ----------
        float nh[D];
        if (lev == 0) {
#pragma unroll
            for (int j = 0; j < D; ++j)
                nh[j] = fmaf(x0, W0[j],
                        fmaf(x1, W0[D + j],
                        fmaf(x2, W0[2 * D + j], b0[j])));
        } else {
            const float* __restrict__ Wl = Ws + (size_t)(lev - 1) * D * D;
            const float* __restrict__ bl = bs + (size_t)(lev - 1) * D;
#pragma unroll
            for (int j = 0; j < D; ++j) nh[j] = bl[j];
            for (int k = 0; k < D; ++k) {
                float hk = lds_h[k][tid];
                const float* __restrict__ wrow = Wl + (size_t)k * D;
#pragma unroll
                for (int j = 0; j < D; ++j)
                    nh[j] = fmaf(hk, wrow[j], nh[j]);
            }
        }
        // store h for next level + for the rolled proj loop
#pragma unroll
        for (int j = 0; j < D; ++j) lds_h[j][tid] = nh[j];

        // ---------- hash-grid trilinear lookup ----------
        const float res = resarr.r[lev];
        float px = xn0 * res, py = xn1 * res, pz = xn2 * res;
        float fx = floorf(px), fy = floorf(py), fz = floorf(pz);
        float wx = px - fx, wy = py - fy, wz = pz - fz;
        uint32_t ix = (uint32_t)fx, iy = (uint32_t)fy, iz = (uint32_t)fz;
        const float* __restrict__ tab = tables + ((size_t)lev << TBITS) * 2;
        float g0 = 0.0f, g1 = 0.0f;
#pragma unroll
        for (int c = 0; c < 8; ++c) {
            const uint32_t bx = (c >> 2) & 1, by = (c >> 1) & 1, bz = c & 1;
            uint32_t hx = (ix + bx);                       // prime 1
            uint32_t hy = (iy + by) * 2654435761u;
            uint32_t hz = (iz + bz) * 805459861u;
            uint32_t idx = (hx ^ hy ^ hz) & TMASK;
            float f0 = tab[(size_t)idx * 2 + 0];
            float f1 = tab[(size_t)idx * 2 + 1];
            float wcx = bx ? wx : (1.0f - wx);
            float wcy = by ? wy : (1.0f - wy);
            float wcz = bz ? wz : (1.0f - wz);
            float wc = wcx * wcy * wcz;
            g0 = fmaf(wc, f0, g0);
            g1 = fmaf(wc, f1, g1);
        }

        // ---------- proj = (h + g @ Gw + Gb) @ Bmat ----------
        const float* __restrict__ Gw0 = Gw + (size_t)lev * 2 * D;
        const float* __restrict__ Gw1 = Gw0 + D;
        const float* __restrict__ Gbl = Gb + (size_t)lev * D;
        const float* __restrict__ Bl  = Bmat + (size_t)lev * D * HALF_D;
        float proj[HALF_D];
#pragma unroll
        for (int m = 0; m < HALF_D; ++m) proj[m] = 0.0f;
        for (int j = 0; j < D; ++j) {
            float hgj = lds_h[j][tid] + fmaf(g0, Gw0[j], fmaf(g1, Gw1[j], Gbl[j]));
            const float* __restrict__ brow = Bl + (size_t)j * HALF_D;
#pragma unroll
            for (int m = 0; m < HALF_D; ++m)
                proj[m] = fmaf(hgj, brow[m], proj[m]);
        }

        // ---------- fourier + fold into output (acc@Wout distributed) ----------
#pragma unroll
        for (int m = 0; m < HALF_D; ++m) {
            float s = sin2pi(proj[m]);
            float c = cos2pi(proj[m]);
            const float* __restrict__ wsrow = Wout + (size_t)m * NUM_OUT;
            const float* __restrict__ wcrow = Wout + (size_t)(m + HALF_D) * NUM_OUT;
#pragma unroll
            for (int o = 0; o < NUM_OUT; ++o)
                outacc[o] = fmaf(s, wsrow[o], fmaf(c, wcrow[o], outacc[o]));
        }
    }

#pragma unroll
    for (int o = 0; o < NUM_OUT; ++o)
        out[(size_t)n * NUM_OUT + o] = outacc[o] + bout[o];
}

extern "C" void kernel_launch(void* const* d_in, const int* in_sizes, int n_in,
                              void* d_out, int out_size, void* d_ws, size_t ws_size,
                              hipStream_t stream) {
    const float* input  = (const float*)d_in[0];
    const float* W0     = (const float*)d_in[1];
    const float* b0     = (const float*)d_in[2];
    const float* Ws     = (const float*)d_in[3];
    const float* bs     = (const float*)d_in[4];
    const float* tables = (const float*)d_in[5];
    const float* Gw     = (const float*)d_in[6];
    const float* Gb     = (const float*)d_in[7];
    const float* Bmat   = (const float*)d_in[8];
    const float* Wout   = (const float*)d_in[9];
    const float* bout   = (const float*)d_in[10];
    float* out = (float*)d_out;

    const int npts = in_sizes[0] / 3;

    // Replicate the reference's RES computation exactly (double precision,
    // same pow/floor chain) to avoid the floor(16*g^7)=511-vs-512 hazard.
    ResArr ra;
    const double growth = pow(512.0 / 16.0, 1.0 / (double)(N_LEVELS - 1));
    for (int i = 0; i < N_LEVELS; ++i)
        ra.r[i] = (float)floor(16.0 * pow(growth, (double)i));

    const int blocks = (npts + BLK - 1) / BLK;
    hipLaunchKernelGGL(ffb_kernel, dim3(blocks), dim3(BLK), 0, stream,
                       input, W0, b0, Ws, bs, tables, Gw, Gb, Bmat, Wout, bout,
                       out, npts, ra);
}

// Round 3
// 765.013 us; speedup vs baseline: 3.9330x; 3.9330x over previous
//
#include <hip/hip_runtime.h>
#include <math.h>
#include <stdint.h>

#define N_LEVELS 8
#define TBITS 19
#define TMASK ((1u << TBITS) - 1u)
#define BLK 128

typedef __attribute__((ext_vector_type(8))) short short8;
typedef __attribute__((ext_vector_type(4))) float f32x4;
typedef unsigned int uint;
typedef unsigned short ushort;

// ---- workspace layout (bytes) ----
// wsW : [7][2(s)][4(mb)][2(ks)][64(lane)][8] bf16  -> A-frags of Ws^T
// wsB : [8][2(s)][2(mb)][2(ks)][64][8] bf16        -> A-frags of Bmat^T
// wsWo: [2(s)][2(ks)][64][8] bf16                  -> A-frags of Wout^T
// wsP : [8][3][32] f32                             -> P0,P1,P2 per level
#define WSW_OFF   0
#define WSW_N     (7 * 2 * 4 * 2 * 512)      // ushort count = 57344
#define WSB_OFF   (WSW_N * 2)                // 114688 B
#define WSB_N     (8 * 2 * 2 * 2 * 512)      // 32768
#define WSWO_OFF  (WSB_OFF + WSB_N * 2)      // 180224 B
#define WSWO_N    (2 * 2 * 512)              // 2048
#define WSP_OFF   (WSWO_OFF + WSWO_N * 2)    // 184320 B
#define WSP_N     (8 * 3 * 32)               // 768 floats
#define WS_NEEDED ((size_t)(WSP_OFF + WSP_N * 4))   // 187392 B

struct ResArr { float r[N_LEVELS]; };

// XOR-swizzled LDS index for [32][64] ushort tiles (bank-conflict-free b128)
#define HIDX(pt, ch) ((((pt) << 6) | (ch)) ^ (((pt) & 7) << 3))

__device__ __forceinline__ ushort f2bf(float f) {
    uint u = __float_as_uint(f);
    u += 0x7fffu + ((u >> 16) & 1u);
    return (ushort)(u >> 16);
}
__device__ __forceinline__ float bf2f(ushort h) {
    return __uint_as_float(((uint)h) << 16);
}
__device__ __forceinline__ uint cvtpk(float a, float b) {
    uint r;
    asm("v_cvt_pk_bf16_f32 %0, %1, %2" : "=v"(r) : "v"(a), "v"(b));
    return r;
}
__device__ __forceinline__ short8 ldfragG(const void* p) {
    return __builtin_bit_cast(short8, *(const uint4*)p);
}
__device__ __forceinline__ short8 ldfragL(const ushort* p) {
    return __builtin_bit_cast(short8, *(const uint4*)p);
}
__device__ __forceinline__ f32x4 MFMA(short8 a, short8 b, f32x4 c) {
    return __builtin_amdgcn_mfma_f32_16x16x32_bf16(a, b, c, 0, 0, 0);
}
__device__ __forceinline__ f32x4 zero4() {
    f32x4 z; z[0] = 0.f; z[1] = 0.f; z[2] = 0.f; z[3] = 0.f; return z;
}
__device__ __forceinline__ float sin2pi(float t) {
    float f = t - floorf(t);
    return __builtin_amdgcn_sinf(f);
}
__device__ __forceinline__ float cos2pi(float t) {
    float f = t - floorf(t);
    return __builtin_amdgcn_cosf(f);
}

// ================= prep kernel: weights -> frag-layout bf16 hi/lo =================
__global__ void prep_kernel(const float* __restrict__ Ws,
                            const float* __restrict__ Bmat,
                            const float* __restrict__ Wout,
                            const float* __restrict__ Gw,
                            const float* __restrict__ Gb,
                            void* __restrict__ ws)
{
    const int NW = WSW_N, NB = WSB_N, NWO = WSWO_N;
    const int NTOT = NW + NB + NWO + WSP_N;
    int t = blockIdx.x * 256 + threadIdx.x;
    if (t >= NTOT) return;
    ushort* w16 = (ushort*)ws;
    float* wsP = (float*)((char*)ws + WSP_OFF);

    if (t < NW) {
        int i = t & 7, lane = (t >> 3) & 63, ks = (t >> 9) & 1;
        int mb = (t >> 10) & 3, s = (t >> 12) & 1, lv = t >> 13;
        int gl = lane >> 4, il = lane & 15;
        int k = ks * 32 + gl * 8 + i, m = mb * 16 + il;
        float v = Ws[lv * 4096 + k * 64 + m];
        ushort hi = f2bf(v);
        w16[t] = s ? f2bf(v - bf2f(hi)) : hi;
    } else if (t < NW + NB) {
        int u = t - NW;
        int i = u & 7, lane = (u >> 3) & 63, ks = (u >> 9) & 1;
        int mb = (u >> 10) & 1, s = (u >> 11) & 1, lv = u >> 12;
        int gl = lane >> 4, il = lane & 15;
        int k = ks * 32 + gl * 8 + i, m = mb * 16 + il;
        float v = Bmat[lv * 2048 + k * 32 + m];
        ushort hi = f2bf(v);
        w16[NW + u] = s ? f2bf(v - bf2f(hi)) : hi;
    } else if (t < NW + NB + NWO) {
        int u = t - NW - NB;
        int i = u & 7, lane = (u >> 3) & 63, ks = (u >> 9) & 1, s = (u >> 10) & 1;
        int gl = lane >> 4, il = lane & 15;
        int k = ks * 32 + gl * 8 + i;
        float v = Wout[k * 16 + il];
        ushort hi = f2bf(v);
        w16[(WSWO_OFF / 2) + u] = s ? f2bf(v - bf2f(hi)) : hi;
    } else {
        int u = t - NW - NB - NWO;
        int lv = u / 96, rem = u % 96, wh = rem >> 5, m = rem & 31;
        const float* src = (wh == 0) ? (Gw + lv * 128)
                         : (wh == 1) ? (Gw + lv * 128 + 64)
                                     : (Gb + lv * 64);
        float acc = 0.f;
        for (int j = 0; j < 64; ++j)
            acc = fmaf(src[j], Bmat[lv * 2048 + j * 32 + m], acc);
        wsP[lv * 96 + wh * 32 + m] = acc;
    }
}

// ================= main kernel: 1 wave, 32 points =================
__global__ __launch_bounds__(64) void ffb_mfma(
    const float* __restrict__ input,
    const float* __restrict__ W0,
    const float* __restrict__ b0,
    const float* __restrict__ bs,
    const float* __restrict__ tables,
    const float* __restrict__ bout,
    const void* __restrict__ ws,
    float* __restrict__ out,
    int npts, ResArr ra)
{
    __shared__ __attribute__((aligned(16))) ushort sHhi[2048];
    __shared__ __attribute__((aligned(16))) ushort sHlo[2048];
    __shared__ __attribute__((aligned(16))) ushort sF[2048];
    __shared__ float sW0[256];
    __shared__ float sP[96];
    __shared__ float sBias[64];
    __shared__ float sG[64];
    __shared__ float sBout[16];

    const int l = threadIdx.x;
    const int il = l & 15, gl = l >> 4;
    const int base = blockIdx.x * 32;
    const int p = l & 31;
    const char* wsc = (const char*)ws;
    const float* wsP = (const float*)(wsc + WSP_OFF);

    // per-lane point coords (lanes l and l+32 duplicate point p = l&31)
    float x0 = input[(size_t)(base + p) * 3 + 0] * (1.0f / 1.5f);
    float x1 = input[(size_t)(base + p) * 3 + 1] * (1.0f / 1.5f);
    float x2 = input[(size_t)(base + p) * 3 + 2] * (1.0f / 1.5f);
    const float hiclip = (float)(1.0 - 1e-6);
    float xn0 = fminf(fmaxf((x0 + 1.0f) * 0.5f, 0.0f), hiclip);
    float xn1 = fminf(fmaxf((x1 + 1.0f) * 0.5f, 0.0f), hiclip);
    float xn2 = fminf(fmaxf((x2 + 1.0f) * 0.5f, 0.0f), hiclip);

    // Wout A-frags (level-independent, hi plane only)
    short8 aWo[2];
#pragma unroll
    for (int ks = 0; ks < 2; ++ks)
        aWo[ks] = ldfragG(wsc + WSWO_OFF + (size_t)(0 * 2 + ks) * 1024 + l * 16);

    f32x4 outacc[2];
    outacc[0] = zero4(); outacc[1] = zero4();
    short8 bH[2][2][2];   // [s][ks][nb] B-frags of current h

    for (int lev = 0; lev < N_LEVELS; ++lev) {
        // ---------------- stage ----------------
        if (lev == 0) {
            for (int j = l; j < 192; j += 64) sW0[j] = W0[j];
            sW0[192 + l] = b0[l];
            if (l < 16) sBout[l] = bout[l];
        } else {
            sBias[l] = bs[(lev - 1) * 64 + l];
        }
        sP[l] = wsP[lev * 96 + l];
        if (l < 32) sP[64 + l] = wsP[lev * 96 + 64 + l];
        if (l < 32) {
            // hash-grid trilinear gather for point p = l
            const float res = ra.r[lev];
            float px = xn0 * res, py = xn1 * res, pz = xn2 * res;
            float fx = floorf(px), fy = floorf(py), fz = floorf(pz);
            float wx = px - fx, wy = py - fy, wz = pz - fz;
            uint ix = (uint)fx, iy = (uint)fy, iz = (uint)fz;
            const float* __restrict__ tab = tables + (((size_t)lev) << TBITS) * 2;
            float g0 = 0.f, g1 = 0.f;
#pragma unroll
            for (int c = 0; c < 8; ++c) {
                const uint bx = (c >> 2) & 1, by = (c >> 1) & 1, bz = c & 1;
                uint hx = ix + bx;
                uint hy = (iy + by) * 2654435761u;
                uint hz = (iz + bz) * 805459861u;
                uint idx = (hx ^ hy ^ hz) & TMASK;
                float f0 = tab[(size_t)idx * 2 + 0];
                float f1 = tab[(size_t)idx * 2 + 1];
                float wc = (bx ? wx : 1.0f - wx) * (by ? wy : 1.0f - wy) * (bz ? wz : 1.0f - wz);
                g0 = fmaf(wc, f0, g0);
                g1 = fmaf(wc, f1, g1);
            }
            sG[2 * l] = g0; sG[2 * l + 1] = g1;
        }
        __syncthreads();   // (A) staging visible

        if (lev == 0) {
            // h0 = x@W0 + b0 via VALU; lanes split channel halves
            const int chb = (l >> 5) * 32;
#pragma unroll
            for (int cc = 0; cc < 32; cc += 2) {
                int ch = chb + cc;
                float v0 = fmaf(x0, sW0[ch],     fmaf(x1, sW0[64 + ch],     fmaf(x2, sW0[128 + ch],     sW0[192 + ch])));
                float v1 = fmaf(x0, sW0[ch + 1], fmaf(x1, sW0[64 + ch + 1], fmaf(x2, sW0[128 + ch + 1], sW0[192 + ch + 1])));
                uint pk = cvtpk(v0, v1);
                float r0 = v0 - __uint_as_float(pk << 16);
                float r1 = v1 - __uint_as_float(pk & 0xffff0000u);
                uint pklo = cvtpk(r0, r1);
                uint idx = HIDX(p, ch);
                *(uint*)&sHhi[idx] = pk;
                *(uint*)&sHlo[idx] = pklo;
            }
        } else {
            // GEMM1: Hnew^T = Ws^T x H^T (split-bf16, 48 MFMA)
            f32x4 acc[4][2];
#pragma unroll
            for (int mb = 0; mb < 4; ++mb)
#pragma unroll
                for (int nb = 0; nb < 2; ++nb) acc[mb][nb] = zero4();
#pragma unroll
            for (int mb = 0; mb < 4; ++mb) {
                short8 aHi[2], aLo[2];
#pragma unroll
                for (int ks = 0; ks < 2; ++ks) {
                    aHi[ks] = ldfragG(wsc + WSW_OFF + (size_t)((((lev - 1) * 2 + 0) * 4 + mb) * 2 + ks) * 1024 + l * 16);
                    aLo[ks] = ldfragG(wsc + WSW_OFF + (size_t)((((lev - 1) * 2 + 1) * 4 + mb) * 2 + ks) * 1024 + l * 16);
                }
#pragma unroll
                for (int nb = 0; nb < 2; ++nb)
#pragma unroll
                    for (int ks = 0; ks < 2; ++ks) {
                        acc[mb][nb] = MFMA(aHi[ks], bH[0][ks][nb], acc[mb][nb]);
                        acc[mb][nb] = MFMA(aLo[ks], bH[0][ks][nb], acc[mb][nb]);
                        acc[mb][nb] = MFMA(aHi[ks], bH[1][ks][nb], acc[mb][nb]);
                    }
            }
            // epilogue: + bias, split hi/lo, write H to LDS
#pragma unroll
            for (int mb = 0; mb < 4; ++mb)
#pragma unroll
                for (int nb = 0; nb < 2; ++nb) {
                    int pt = nb * 16 + il, ch0 = mb * 16 + gl * 4;
                    float2 ba = *(float2*)&sBias[ch0];
                    float2 bb = *(float2*)&sBias[ch0 + 2];
                    float v0 = acc[mb][nb][0] + ba.x, v1 = acc[mb][nb][1] + ba.y;
                    float v2 = acc[mb][nb][2] + bb.x, v3 = acc[mb][nb][3] + bb.y;
                    uint pkA = cvtpk(v0, v1), pkB = cvtpk(v2, v3);
                    float r0 = v0 - __uint_as_float(pkA << 16);
                    float r1 = v1 - __uint_as_float(pkA & 0xffff0000u);
                    float r2 = v2 - __uint_as_float(pkB << 16);
                    float r3 = v3 - __uint_as_float(pkB & 0xffff0000u);
                    uint pkLA = cvtpk(r0, r1), pkLB = cvtpk(r2, r3);
                    uint idx = HIDX(pt, ch0);
                    *(uint*)&sHhi[idx] = pkA;  *(uint*)&sHhi[idx + 2] = pkB;
                    *(uint*)&sHlo[idx] = pkLA; *(uint*)&sHlo[idx + 2] = pkLB;
                }
        }
        __syncthreads();   // (B) H ready

        // B-frags of current h (serve GEMM2 now and GEMM1 next level)
#pragma unroll
        for (int ks = 0; ks < 2; ++ks)
#pragma unroll
            for (int nb = 0; nb < 2; ++nb) {
                int pt = nb * 16 + il;
                uint idx = HIDX(pt, ks * 32 + gl * 8);
                bH[0][ks][nb] = ldfragL(&sHhi[idx]);
                bH[1][ks][nb] = ldfragL(&sHlo[idx]);
            }

        // GEMM2: proj^T = Bmat^T x H^T (split-bf16, 24 MFMA)
        f32x4 pacc[2][2];
#pragma unroll
        for (int mb = 0; mb < 2; ++mb)
#pragma unroll
            for (int nb = 0; nb < 2; ++nb) pacc[mb][nb] = zero4();
#pragma unroll
        for (int mb = 0; mb < 2; ++mb) {
            short8 aBhi[2], aBlo[2];
#pragma unroll
            for (int ks = 0; ks < 2; ++ks) {
                aBhi[ks] = ldfragG(wsc + WSB_OFF + (size_t)(((lev * 2 + 0) * 2 + mb) * 2 + ks) * 1024 + l * 16);
                aBlo[ks] = ldfragG(wsc + WSB_OFF + (size_t)(((lev * 2 + 1) * 2 + mb) * 2 + ks) * 1024 + l * 16);
            }
#pragma unroll
            for (int nb = 0; nb < 2; ++nb)
#pragma unroll
                for (int ks = 0; ks < 2; ++ks) {
                    pacc[mb][nb] = MFMA(aBhi[ks], bH[0][ks][nb], pacc[mb][nb]);
                    pacc[mb][nb] = MFMA(aBlo[ks], bH[0][ks][nb], pacc[mb][nb]);
                    pacc[mb][nb] = MFMA(aBhi[ks], bH[1][ks][nb], pacc[mb][nb]);
                }
        }

        // epilogue: proj += g0*P0 + g1*P1 + P2 ; sin/cos -> sF (bf16)
#pragma unroll
        for (int mb = 0; mb < 2; ++mb)
#pragma unroll
            for (int nb = 0; nb < 2; ++nb) {
                int pt = nb * 16 + il, m0 = mb * 16 + gl * 4;
                float2 g   = *(float2*)&sG[pt * 2];
                float2 p0a = *(float2*)&sP[m0],      p0b = *(float2*)&sP[m0 + 2];
                float2 p1a = *(float2*)&sP[32 + m0], p1b = *(float2*)&sP[32 + m0 + 2];
                float2 p2a = *(float2*)&sP[64 + m0], p2b = *(float2*)&sP[64 + m0 + 2];
                float t0 = pacc[mb][nb][0] + fmaf(g.x, p0a.x, fmaf(g.y, p1a.x, p2a.x));
                float t1 = pacc[mb][nb][1] + fmaf(g.x, p0a.y, fmaf(g.y, p1a.y, p2a.y));
                float t2 = pacc[mb][nb][2] + fmaf(g.x, p0b.x, fmaf(g.y, p1b.x, p2b.x));
                float t3 = pacc[mb][nb][3] + fmaf(g.x, p0b.y, fmaf(g.y, p1b.y, p2b.y));
                float s0 = sin2pi(t0), s1 = sin2pi(t1), s2 = sin2pi(t2), s3 = sin2pi(t3);
                float c0 = cos2pi(t0), c1 = cos2pi(t1), c2 = cos2pi(t2), c3 = cos2pi(t3);
                uint idxs = HIDX(pt, m0), idxc = HIDX(pt, 32 + m0);
                *(uint*)&sF[idxs]     = cvtpk(s0, s1);
                *(uint*)&sF[idxs + 2] = cvtpk(s2, s3);
                *(uint*)&sF[idxc]     = cvtpk(c0, c1);
                *(uint*)&sF[idxc + 2] = cvtpk(c2, c3);
            }
        __syncthreads();   // (C) F ready

        // GEMM3: out^T += Wout^T x F^T (4 MFMA)
#pragma unroll
        for (int nb = 0; nb < 2; ++nb)
#pragma unroll
            for (int ks = 0; ks < 2; ++ks) {
                int pt = nb * 16 + il;
                short8 bF = ldfragL(&sF[HIDX(pt, ks * 32 + gl * 8)]);
                outacc[nb] = MFMA(aWo[ks], bF, outacc[nb]);
            }
    }

    // store: lane holds point pt = nb*16+il, out-channels gl*4..gl*4+3
#pragma unroll
    for (int nb = 0; nb < 2; ++nb) {
        int pt = nb * 16 + il;
        float4 v;
        v.x = outacc[nb][0] + sBout[gl * 4 + 0];
        v.y = outacc[nb][1] + sBout[gl * 4 + 1];
        v.z = outacc[nb][2] + sBout[gl * 4 + 2];
        v.w = outacc[nb][3] + sBout[gl * 4 + 3];
        *(float4*)(&out[(size_t)(base + pt) * 16 + gl * 4]) = v;
    }
}

// ================= fallback: round-1 pure-VALU kernel (no workspace) =================
__global__ __launch_bounds__(BLK) void ffb_valu(
    const float* __restrict__ input,
    const float* __restrict__ W0,
    const float* __restrict__ b0,
    const float* __restrict__ Ws,
    const float* __restrict__ bs,
    const float* __restrict__ tables,
    const float* __restrict__ Gw,
    const float* __restrict__ Gb,
    const float* __restrict__ Bmat,
    const float* __restrict__ Wout,
    const float* __restrict__ bout,
    float* __restrict__ out,
    int npts, ResArr resarr)
{
    __shared__ float lds_h[64][BLK];

    const int tid = threadIdx.x;
    const int n = blockIdx.x * BLK + tid;
    if (n >= npts) return;

    float x0 = input[(size_t)n * 3 + 0] / 1.5f;
    float x1 = input[(size_t)n * 3 + 1] / 1.5f;
    float x2 = input[(size_t)n * 3 + 2] / 1.5f;
    const float hi = (float)(1.0 - 1e-6);
    float xn0 = fminf(fmaxf((x0 + 1.0f) * 0.5f, 0.0f), hi);
    float xn1 = fminf(fmaxf((x1 + 1.0f) * 0.5f, 0.0f), hi);
    float xn2 = fminf(fmaxf((x2 + 1.0f) * 0.5f, 0.0f), hi);

    float outacc[16];
#pragma unroll
    for (int o = 0; o < 16; ++o) outacc[o] = 0.0f;

    for (int lev = 0; lev < N_LEVELS; ++lev) {
        float nh[64];
        if (lev == 0) {
#pragma unroll
            for (int j = 0; j < 64; ++j)
                nh[j] = fmaf(x0, W0[j], fmaf(x1, W0[64 + j], fmaf(x2, W0[128 + j], b0[j])));
        } else {
            const float* __restrict__ Wl = Ws + (size_t)(lev - 1) * 4096;
            const float* __restrict__ bl = bs + (size_t)(lev - 1) * 64;
#pragma unroll
            for (int j = 0; j < 64; ++j) nh[j] = bl[j];
            for (int k = 0; k < 64; ++k) {
                float hk = lds_h[k][tid];
                const float* __restrict__ wrow = Wl + (size_t)k * 64;
#pragma unroll
                for (int j = 0; j < 64; ++j)
                    nh[j] = fmaf(hk, wrow[j], nh[j]);
            }
        }
#pragma unroll
        for (int j = 0; j < 64; ++j) lds_h[j][tid] = nh[j];

        const float res = resarr.r[lev];
        float px = xn0 * res, py = xn1 * res, pz = xn2 * res;
        float fx = floorf(px), fy = floorf(py), fz = floorf(pz);
        float wx = px - fx, wy = py - fy, wz = pz - fz;
        uint32_t ix = (uint32_t)fx, iy = (uint32_t)fy, iz = (uint32_t)fz;
        const float* __restrict__ tab = tables + ((size_t)lev << TBITS) * 2;
        float g0 = 0.0f, g1 = 0.0f;
#pragma unroll
        for (int c = 0; c < 8; ++c) {
            const uint32_t bx = (c >> 2) & 1, by = (c >> 1) & 1, bz = c & 1;
            uint32_t hx = (ix + bx);
            uint32_t hy = (iy + by) * 2654435761u;
            uint32_t hz = (iz + bz) * 805459861u;
            uint32_t idx = (hx ^ hy ^ hz) & TMASK;
            float f0 = tab[(size_t)idx * 2 + 0];
            float f1 = tab[(size_t)idx * 2 + 1];
            float wc = (bx ? wx : 1.0f - wx) * (by ? wy : 1.0f - wy) * (bz ? wz : 1.0f - wz);
            g0 = fmaf(wc, f0, g0);
            g1 = fmaf(wc, f1, g1);
        }

        const float* __restrict__ Gw0 = Gw + (size_t)lev * 128;
        const float* __restrict__ Gw1 = Gw0 + 64;
        const float* __restrict__ Gbl = Gb + (size_t)lev * 64;
        const float* __restrict__ Bl  = Bmat + (size_t)lev * 2048;
        float proj[32];
#pragma unroll
        for (int m = 0; m < 32; ++m) proj[m] = 0.0f;
        for (int j = 0; j < 64; ++j) {
            float hgj = lds_h[j][tid] + fmaf(g0, Gw0[j], fmaf(g1, Gw1[j], Gbl[j]));
            const float* __restrict__ brow = Bl + (size_t)j * 32;
#pragma unroll
            for (int m = 0; m < 32; ++m)
                proj[m] = fmaf(hgj, brow[m], proj[m]);
        }

#pragma unroll
        for (int m = 0; m < 32; ++m) {
            float s = sin2pi(proj[m]);
            float c = cos2pi(proj[m]);
            const float* __restrict__ wsrow = Wout + (size_t)m * 16;
            const float* __restrict__ wcrow = Wout + (size_t)(m + 32) * 16;
#pragma unroll
            for (int o = 0; o < 16; ++o)
                outacc[o] = fmaf(s, wsrow[o], fmaf(c, wcrow[o], outacc[o]));
        }
    }

#pragma unroll
    for (int o = 0; o < 16; ++o)
        out[(size_t)n * 16 + o] = outacc[o] + bout[o];
}

extern "C" void kernel_launch(void* const* d_in, const int* in_sizes, int n_in,
                              void* d_out, int out_size, void* d_ws, size_t ws_size,
                              hipStream_t stream) {
    const float* input  = (const float*)d_in[0];
    const float* W0     = (const float*)d_in[1];
    const float* b0     = (const float*)d_in[2];
    const float* Ws     = (const float*)d_in[3];
    const float* bs     = (const float*)d_in[4];
    const float* tables = (const float*)d_in[5];
    const float* Gw     = (const float*)d_in[6];
    const float* Gb     = (const float*)d_in[7];
    const float* Bmat   = (const float*)d_in[8];
    const float* Wout   = (const float*)d_in[9];
    const float* bout   = (const float*)d_in[10];
    float* out = (float*)d_out;

    const int npts = in_sizes[0] / 3;

    // Replicate the reference's RES computation exactly (double precision).
    ResArr ra;
    const double growth = pow(512.0 / 16.0, 1.0 / (double)(N_LEVELS - 1));
    for (int i = 0; i < N_LEVELS; ++i)
        ra.r[i] = (float)floor(16.0 * pow(growth, (double)i));

    if (ws_size >= WS_NEEDED && (npts % 32) == 0) {
        const int NTOT = WSW_N + WSB_N + WSWO_N + WSP_N;   // 92928
        hipLaunchKernelGGL(prep_kernel, dim3((NTOT + 255) / 256), dim3(256), 0, stream,
                           Ws, Bmat, Wout, Gw, Gb, d_ws);
        hipLaunchKernelGGL(ffb_mfma, dim3(npts / 32), dim3(64), 0, stream,
                           input, W0, b0, bs, tables, bout, d_ws, out, npts, ra);
    } else {
        hipLaunchKernelGGL(ffb_valu, dim3((npts + BLK - 1) / BLK), dim3(BLK), 0, stream,
                           input, W0, b0, Ws, bs, tables, Gw, Gb, Bmat, Wout, bout,
                           out, npts, ra);
    }
}

// Round 4
// 691.416 us; speedup vs baseline: 4.3516x; 1.1064x over previous
//
#include <hip/hip_runtime.h>
#include <math.h>
#include <stdint.h>

#define N_LEVELS 8
#define TBITS 19
#define TMASK ((1u << TBITS) - 1u)
#define BLK 128

typedef __attribute__((ext_vector_type(8))) short short8;
typedef __attribute__((ext_vector_type(4))) float f32x4;
typedef unsigned int uint;
typedef unsigned short ushort;

// ---- workspace layout (bytes) ----
// wsW : [7][2(s)][4(mb)][2(ks)][64(lane)][8] bf16  -> A-frags of Ws^T
// wsB : [8][2(s)][2(mb)][2(ks)][64][8] bf16        -> A-frags of Bmat^T
// wsWo: [2(s)][2(ks)][64][8] bf16                  -> A-frags of Wout^T
// wsP : [8][3][32] f32                             -> P0,P1,P2 per level
#define WSW_OFF   0
#define WSW_N     (7 * 2 * 4 * 2 * 512)      // ushort count = 57344
#define WSB_OFF   (WSW_N * 2)                // 114688 B
#define WSB_N     (8 * 2 * 2 * 2 * 512)      // 32768
#define WSWO_OFF  (WSB_OFF + WSB_N * 2)      // 180224 B
#define WSWO_N    (2 * 2 * 512)              // 2048
#define WSP_OFF   (WSWO_OFF + WSWO_N * 2)    // 184320 B
#define WSP_N     (8 * 3 * 32)               // 768 floats
#define WS_NEEDED ((size_t)(WSP_OFF + WSP_N * 4))   // 187392 B

struct ResArr { float r[N_LEVELS]; };

// XOR-swizzled LDS index for [32][64] ushort tiles (bank-conflict-reduced b128)
#define HIDX(pt, ch) ((((pt) << 6) | (ch)) ^ (((pt) & 7) << 3))
#define HLO 2048   // lo-plane / F-plane offset inside sH (aliased regions)

__device__ __forceinline__ ushort f2bf(float f) {
    uint u = __float_as_uint(f);
    u += 0x7fffu + ((u >> 16) & 1u);
    return (ushort)(u >> 16);
}
__device__ __forceinline__ float bf2f(ushort h) {
    return __uint_as_float(((uint)h) << 16);
}
__device__ __forceinline__ uint cvtpk(float a, float b) {
    uint r;
    asm("v_cvt_pk_bf16_f32 %0, %1, %2" : "=v"(r) : "v"(a), "v"(b));
    return r;
}
__device__ __forceinline__ short8 ldfragG(const void* p) {
    return __builtin_bit_cast(short8, *(const uint4*)p);
}
__device__ __forceinline__ short8 ldfragL(const ushort* p) {
    return __builtin_bit_cast(short8, *(const uint4*)p);
}
__device__ __forceinline__ f32x4 MFMA(short8 a, short8 b, f32x4 c) {
    return __builtin_amdgcn_mfma_f32_16x16x32_bf16(a, b, c, 0, 0, 0);
}
__device__ __forceinline__ f32x4 zero4() {
    f32x4 z; z[0] = 0.f; z[1] = 0.f; z[2] = 0.f; z[3] = 0.f; return z;
}
__device__ __forceinline__ float sin2pi(float t) {
    return __builtin_amdgcn_sinf(__builtin_amdgcn_fractf(t));   // v_fract + v_sin
}
__device__ __forceinline__ float cos2pi(float t) {
    return __builtin_amdgcn_cosf(__builtin_amdgcn_fractf(t));
}

// ================= prep kernel: weights -> frag-layout bf16 hi/lo =================
__global__ void prep_kernel(const float* __restrict__ Ws,
                            const float* __restrict__ Bmat,
                            const float* __restrict__ Wout,
                            const float* __restrict__ Gw,
                            const float* __restrict__ Gb,
                            void* __restrict__ ws)
{
    const int NW = WSW_N, NB = WSB_N, NWO = WSWO_N;
    const int NTOT = NW + NB + NWO + WSP_N;
    int t = blockIdx.x * 256 + threadIdx.x;
    if (t >= NTOT) return;
    ushort* w16 = (ushort*)ws;
    float* wsP = (float*)((char*)ws + WSP_OFF);

    if (t < NW) {
        int i = t & 7, lane = (t >> 3) & 63, ks = (t >> 9) & 1;
        int mb = (t >> 10) & 3, s = (t >> 12) & 1, lv = t >> 13;
        int gl = lane >> 4, il = lane & 15;
        int k = ks * 32 + gl * 8 + i, m = mb * 16 + il;
        float v = Ws[lv * 4096 + k * 64 + m];
        ushort hi = f2bf(v);
        w16[t] = s ? f2bf(v - bf2f(hi)) : hi;
    } else if (t < NW + NB) {
        int u = t - NW;
        int i = u & 7, lane = (u >> 3) & 63, ks = (u >> 9) & 1;
        int mb = (u >> 10) & 1, s = (u >> 11) & 1, lv = u >> 12;
        int gl = lane >> 4, il = lane & 15;
        int k = ks * 32 + gl * 8 + i, m = mb * 16 + il;
        float v = Bmat[lv * 2048 + k * 32 + m];
        ushort hi = f2bf(v);
        w16[NW + u] = s ? f2bf(v - bf2f(hi)) : hi;
    } else if (t < NW + NB + NWO) {
        int u = t - NW - NB;
        int i = u & 7, lane = (u >> 3) & 63, ks = (u >> 9) & 1, s = (u >> 10) & 1;
        int gl = lane >> 4, il = lane & 15;
        int k = ks * 32 + gl * 8 + i;
        float v = Wout[k * 16 + il];
        ushort hi = f2bf(v);
        w16[(WSWO_OFF / 2) + u] = s ? f2bf(v - bf2f(hi)) : hi;
    } else {
        int u = t - NW - NB - NWO;
        int lv = u / 96, rem = u % 96, wh = rem >> 5, m = rem & 31;
        const float* src = (wh == 0) ? (Gw + lv * 128)
                         : (wh == 1) ? (Gw + lv * 128 + 64)
                                     : (Gb + lv * 64);
        float acc = 0.f;
        for (int j = 0; j < 64; ++j)
            acc = fmaf(src[j], Bmat[lv * 2048 + j * 32 + m], acc);
        wsP[lv * 96 + wh * 32 + m] = acc;
    }
}

// ================= main kernel: 1 wave, 32 points =================
__global__ __launch_bounds__(64, 4) void ffb_mfma(
    const float* __restrict__ input,
    const float* __restrict__ W0,
    const float* __restrict__ b0,
    const float* __restrict__ bs,
    const float* __restrict__ tables,
    const float* __restrict__ bout,
    const void* __restrict__ ws,
    float* __restrict__ out,
    int npts, ResArr ra)
{
    // sH[0..2047]    : H hi-plane  ([32pt][64ch] ushort, HIDX-swizzled)
    // sH[2048..4095] : H lo-plane, later ALIASED by the F (sin/cos) tile.
    //   Safe because the lo-plane's last read (bH[1] frag load, after barrier B)
    //   precedes the first F write in every level, and with a single wave the
    //   compiler orders same-array LDS ops via lgkmcnt.
    __shared__ __attribute__((aligned(16))) ushort sH[4096];
    __shared__ float sP[96];
    __shared__ float sBias[64];
    __shared__ float sG[64];

    const int l = threadIdx.x;
    const int il = l & 15, gl = l >> 4;
    const int base = blockIdx.x * 32;
    const int p = l & 31;
    const char* wsc = (const char*)ws;
    const float* wsP = (const float*)(wsc + WSP_OFF);

    // per-lane point coords (lanes l and l+32 duplicate point p = l&31)
    float x0 = input[(size_t)(base + p) * 3 + 0] * (1.0f / 1.5f);
    float x1 = input[(size_t)(base + p) * 3 + 1] * (1.0f / 1.5f);
    float x2 = input[(size_t)(base + p) * 3 + 2] * (1.0f / 1.5f);
    const float hiclip = (float)(1.0 - 1e-6);
    float xn0 = fminf(fmaxf((x0 + 1.0f) * 0.5f, 0.0f), hiclip);
    float xn1 = fminf(fmaxf((x1 + 1.0f) * 0.5f, 0.0f), hiclip);
    float xn2 = fminf(fmaxf((x2 + 1.0f) * 0.5f, 0.0f), hiclip);

    // Wout A-frags (level-independent, hi plane only)
    short8 aWo[2];
#pragma unroll
    for (int ks = 0; ks < 2; ++ks)
        aWo[ks] = ldfragG(wsc + WSWO_OFF + (size_t)ks * 1024 + l * 16);

    f32x4 outacc[2];
    outacc[0] = zero4(); outacc[1] = zero4();
    short8 bH[2][2][2];   // [s][ks][nb] B-frags of current h

    for (int lev = 0; lev < N_LEVELS; ++lev) {
        // ---------------- stage ----------------
        if (lev > 0) sBias[l] = bs[(lev - 1) * 64 + l];
        sP[l] = wsP[lev * 96 + l];
        if (l < 32) sP[64 + l] = wsP[lev * 96 + 64 + l];
        if (l < 32) {
            // hash-grid trilinear gather for point p = l
            const float res = ra.r[lev];
            float px = xn0 * res, py = xn1 * res, pz = xn2 * res;
            float fx = floorf(px), fy = floorf(py), fz = floorf(pz);
            float wx = px - fx, wy = py - fy, wz = pz - fz;
            uint ix = (uint)fx, iy = (uint)fy, iz = (uint)fz;
            const float* __restrict__ tab = tables + (((size_t)lev) << TBITS) * 2;
            float g0 = 0.f, g1 = 0.f;
#pragma unroll
            for (int c = 0; c < 8; ++c) {
                const uint bx = (c >> 2) & 1, by = (c >> 1) & 1, bz = c & 1;
                uint hx = ix + bx;
                uint hy = (iy + by) * 2654435761u;
                uint hz = (iz + bz) * 805459861u;
                uint idx = (hx ^ hy ^ hz) & TMASK;
                float f0 = tab[(size_t)idx * 2 + 0];
                float f1 = tab[(size_t)idx * 2 + 1];
                float wc = (bx ? wx : 1.0f - wx) * (by ? wy : 1.0f - wy) * (bz ? wz : 1.0f - wz);
                g0 = fmaf(wc, f0, g0);
                g1 = fmaf(wc, f1, g1);
            }
            sG[2 * l] = g0; sG[2 * l + 1] = g1;
        }
        __syncthreads();   // (A) staging visible

        if (lev == 0) {
            // h0 = x@W0 + b0 via VALU; lanes split channel halves.
            // W0/b0 read straight from global (one-time, L2-hot).
            const int chb = (l >> 5) * 32;
#pragma unroll
            for (int cc = 0; cc < 32; cc += 2) {
                int ch = chb + cc;
                float v0 = fmaf(x0, W0[ch],     fmaf(x1, W0[64 + ch],     fmaf(x2, W0[128 + ch],     b0[ch])));
                float v1 = fmaf(x0, W0[ch + 1], fmaf(x1, W0[64 + ch + 1], fmaf(x2, W0[128 + ch + 1], b0[ch + 1])));
                uint pk = cvtpk(v0, v1);
                float r0 = v0 - __uint_as_float(pk << 16);
                float r1 = v1 - __uint_as_float(pk & 0xffff0000u);
                uint pklo = cvtpk(r0, r1);
                uint idx = HIDX(p, ch);
                *(uint*)&sH[idx] = pk;
                *(uint*)&sH[HLO + idx] = pklo;
            }
        } else {
            // GEMM1: Hnew^T = Ws^T x H^T (split-bf16, 48 MFMA)
            f32x4 acc[4][2];
#pragma unroll
            for (int mb = 0; mb < 4; ++mb)
#pragma unroll
                for (int nb = 0; nb < 2; ++nb) acc[mb][nb] = zero4();
#pragma unroll
            for (int mb = 0; mb < 4; ++mb) {
                short8 aHi[2], aLo[2];
#pragma unroll
                for (int ks = 0; ks < 2; ++ks) {
                    aHi[ks] = ldfragG(wsc + WSW_OFF + (size_t)((((lev - 1) * 2 + 0) * 4 + mb) * 2 + ks) * 1024 + l * 16);
                    aLo[ks] = ldfragG(wsc + WSW_OFF + (size_t)((((lev - 1) * 2 + 1) * 4 + mb) * 2 + ks) * 1024 + l * 16);
                }
#pragma unroll
                for (int nb = 0; nb < 2; ++nb)
#pragma unroll
                    for (int ks = 0; ks < 2; ++ks) {
                        acc[mb][nb] = MFMA(aHi[ks], bH[0][ks][nb], acc[mb][nb]);
                        acc[mb][nb] = MFMA(aLo[ks], bH[0][ks][nb], acc[mb][nb]);
                        acc[mb][nb] = MFMA(aHi[ks], bH[1][ks][nb], acc[mb][nb]);
                    }
            }
            // epilogue: + bias, split hi/lo, write H to LDS
#pragma unroll
            for (int mb = 0; mb < 4; ++mb)
#pragma unroll
                for (int nb = 0; nb < 2; ++nb) {
                    int pt = nb * 16 + il, ch0 = mb * 16 + gl * 4;
                    float2 ba = *(float2*)&sBias[ch0];
                    float2 bb = *(float2*)&sBias[ch0 + 2];
                    float v0 = acc[mb][nb][0] + ba.x, v1 = acc[mb][nb][1] + ba.y;
                    float v2 = acc[mb][nb][2] + bb.x, v3 = acc[mb][nb][3] + bb.y;
                    uint pkA = cvtpk(v0, v1), pkB = cvtpk(v2, v3);
                    float r0 = v0 - __uint_as_float(pkA << 16);
                    float r1 = v1 - __uint_as_float(pkA & 0xffff0000u);
                    float r2 = v2 - __uint_as_float(pkB << 16);
                    float r3 = v3 - __uint_as_float(pkB & 0xffff0000u);
                    uint pkLA = cvtpk(r0, r1), pkLB = cvtpk(r2, r3);
                    uint idx = HIDX(pt, ch0);
                    *(uint*)&sH[idx] = pkA;        *(uint*)&sH[idx + 2] = pkB;
                    *(uint*)&sH[HLO + idx] = pkLA; *(uint*)&sH[HLO + idx + 2] = pkLB;
                }
        }
        __syncthreads();   // (B) H ready

        // B-frags of current h (serve GEMM2 now and GEMM1 next level).
        // Last read of the lo-plane before F aliases it below.
#pragma unroll
        for (int ks = 0; ks < 2; ++ks)
#pragma unroll
            for (int nb = 0; nb < 2; ++nb) {
                int pt = nb * 16 + il;
                uint idx = HIDX(pt, ks * 32 + gl * 8);
                bH[0][ks][nb] = ldfragL(&sH[idx]);
                bH[1][ks][nb] = ldfragL(&sH[HLO + idx]);
            }

        // GEMM2: proj^T = Bmat^T x H^T (split-bf16, 24 MFMA)
        f32x4 pacc[2][2];
#pragma unroll
        for (int mb = 0; mb < 2; ++mb)
#pragma unroll
            for (int nb = 0; nb < 2; ++nb) pacc[mb][nb] = zero4();
#pragma unroll
        for (int mb = 0; mb < 2; ++mb) {
            short8 aBhi[2], aBlo[2];
#pragma unroll
            for (int ks = 0; ks < 2; ++ks) {
                aBhi[ks] = ldfragG(wsc + WSB_OFF + (size_t)(((lev * 2 + 0) * 2 + mb) * 2 + ks) * 1024 + l * 16);
                aBlo[ks] = ldfragG(wsc + WSB_OFF + (size_t)(((lev * 2 + 1) * 2 + mb) * 2 + ks) * 1024 + l * 16);
            }
#pragma unroll
            for (int nb = 0; nb < 2; ++nb)
#pragma unroll
                for (int ks = 0; ks < 2; ++ks) {
                    pacc[mb][nb] = MFMA(aBhi[ks], bH[0][ks][nb], pacc[mb][nb]);
                    pacc[mb][nb] = MFMA(aBlo[ks], bH[0][ks][nb], pacc[mb][nb]);
                    pacc[mb][nb] = MFMA(aBhi[ks], bH[1][ks][nb], pacc[mb][nb]);
                }
        }

        // epilogue: proj += g0*P0 + g1*P1 + P2 ; sin/cos -> F plane (aliases lo)
#pragma unroll
        for (int mb = 0; mb < 2; ++mb)
#pragma unroll
            for (int nb = 0; nb < 2; ++nb) {
                int pt = nb * 16 + il, m0 = mb * 16 + gl * 4;
                float2 g   = *(float2*)&sG[pt * 2];
                float2 p0a = *(float2*)&sP[m0],      p0b = *(float2*)&sP[m0 + 2];
                float2 p1a = *(float2*)&sP[32 + m0], p1b = *(float2*)&sP[32 + m0 + 2];
                float2 p2a = *(float2*)&sP[64 + m0], p2b = *(float2*)&sP[64 + m0 + 2];
                float t0 = pacc[mb][nb][0] + fmaf(g.x, p0a.x, fmaf(g.y, p1a.x, p2a.x));
                float t1 = pacc[mb][nb][1] + fmaf(g.x, p0a.y, fmaf(g.y, p1a.y, p2a.y));
                float t2 = pacc[mb][nb][2] + fmaf(g.x, p0b.x, fmaf(g.y, p1b.x, p2b.x));
                float t3 = pacc[mb][nb][3] + fmaf(g.x, p0b.y, fmaf(g.y, p1b.y, p2b.y));
                float s0 = sin2pi(t0), s1 = sin2pi(t1), s2 = sin2pi(t2), s3 = sin2pi(t3);
                float c0 = cos2pi(t0), c1 = cos2pi(t1), c2 = cos2pi(t2), c3 = cos2pi(t3);
                uint idxs = HIDX(pt, m0), idxc = HIDX(pt, 32 + m0);
                *(uint*)&sH[HLO + idxs]     = cvtpk(s0, s1);
                *(uint*)&sH[HLO + idxs + 2] = cvtpk(s2, s3);
                *(uint*)&sH[HLO + idxc]     = cvtpk(c0, c1);
                *(uint*)&sH[HLO + idxc + 2] = cvtpk(c2, c3);
            }
        __syncthreads();   // (C) F ready

        // GEMM3: out^T += Wout^T x F^T (4 MFMA)
#pragma unroll
        for (int nb = 0; nb < 2; ++nb)
#pragma unroll
            for (int ks = 0; ks < 2; ++ks) {
                int pt = nb * 16 + il;
                short8 bF = ldfragL(&sH[HLO + HIDX(pt, ks * 32 + gl * 8)]);
                outacc[nb] = MFMA(aWo[ks], bF, outacc[nb]);
            }
    }

    // store: lane holds point pt = nb*16+il, out-channels gl*4..gl*4+3
#pragma unroll
    for (int nb = 0; nb < 2; ++nb) {
        int pt = nb * 16 + il;
        float4 v;
        v.x = outacc[nb][0] + bout[gl * 4 + 0];
        v.y = outacc[nb][1] + bout[gl * 4 + 1];
        v.z = outacc[nb][2] + bout[gl * 4 + 2];
        v.w = outacc[nb][3] + bout[gl * 4 + 3];
        *(float4*)(&out[(size_t)(base + pt) * 16 + gl * 4]) = v;
    }
}

// ================= fallback: pure-VALU kernel (no workspace) =================
__global__ __launch_bounds__(BLK) void ffb_valu(
    const float* __restrict__ input,
    const float* __restrict__ W0,
    const float* __restrict__ b0,
    const float* __restrict__ Ws,
    const float* __restrict__ bs,
    const float* __restrict__ tables,
    const float* __restrict__ Gw,
    const float* __restrict__ Gb,
    const float* __restrict__ Bmat,
    const float* __restrict__ Wout,
    const float* __restrict__ bout,
    float* __restrict__ out,
    int npts, ResArr resarr)
{
    __shared__ float lds_h[64][BLK];

    const int tid = threadIdx.x;
    const int n = blockIdx.x * BLK + tid;
    if (n >= npts) return;

    float x0 = input[(size_t)n * 3 + 0] / 1.5f;
    float x1 = input[(size_t)n * 3 + 1] / 1.5f;
    float x2 = input[(size_t)n * 3 + 2] / 1.5f;
    const float hi = (float)(1.0 - 1e-6);
    float xn0 = fminf(fmaxf((x0 + 1.0f) * 0.5f, 0.0f), hi);
    float xn1 = fminf(fmaxf((x1 + 1.0f) * 0.5f, 0.0f), hi);
    float xn2 = fminf(fmaxf((x2 + 1.0f) * 0.5f, 0.0f), hi);

    float outacc[16];
#pragma unroll
    for (int o = 0; o < 16; ++o) outacc[o] = 0.0f;

    for (int lev = 0; lev < N_LEVELS; ++lev) {
        float nh[64];
        if (lev == 0) {
#pragma unroll
            for (int j = 0; j < 64; ++j)
                nh[j] = fmaf(x0, W0[j], fmaf(x1, W0[64 + j], fmaf(x2, W0[128 + j], b0[j])));
        } else {
            const float* __restrict__ Wl = Ws + (size_t)(lev - 1) * 4096;
            const float* __restrict__ bl = bs + (size_t)(lev - 1) * 64;
#pragma unroll
            for (int j = 0; j < 64; ++j) nh[j] = bl[j];
            for (int k = 0; k < 64; ++k) {
                float hk = lds_h[k][tid];
                const float* __restrict__ wrow = Wl + (size_t)k * 64;
#pragma unroll
                for (int j = 0; j < 64; ++j)
                    nh[j] = fmaf(hk, wrow[j], nh[j]);
            }
        }
#pragma unroll
        for (int j = 0; j < 64; ++j) lds_h[j][tid] = nh[j];

        const float res = resarr.r[lev];
        float px = xn0 * res, py = xn1 * res, pz = xn2 * res;
        float fx = floorf(px), fy = floorf(py), fz = floorf(pz);
        float wx = px - fx, wy = py - fy, wz = pz - fz;
        uint32_t ix = (uint32_t)fx, iy = (uint32_t)fy, iz = (uint32_t)fz;
        const float* __restrict__ tab = tables + ((size_t)lev << TBITS) * 2;
        float g0 = 0.0f, g1 = 0.0f;
#pragma unroll
        for (int c = 0; c < 8; ++c) {
            const uint32_t bx = (c >> 2) & 1, by = (c >> 1) & 1, bz = c & 1;
            uint32_t hx = (ix + bx);
            uint32_t hy = (iy + by) * 2654435761u;
            uint32_t hz = (iz + bz) * 805459861u;
            uint32_t idx = (hx ^ hy ^ hz) & TMASK;
            float f0 = tab[(size_t)idx * 2 + 0];
            float f1 = tab[(size_t)idx * 2 + 1];
            float wc = (bx ? wx : 1.0f - wx) * (by ? wy : 1.0f - wy) * (bz ? wz : 1.0f - wz);
            g0 = fmaf(wc, f0, g0);
            g1 = fmaf(wc, f1, g1);
        }

        const float* __restrict__ Gw0 = Gw + (size_t)lev * 128;
        const float* __restrict__ Gw1 = Gw0 + 64;
        const float* __restrict__ Gbl = Gb + (size_t)lev * 64;
        const float* __restrict__ Bl  = Bmat + (size_t)lev * 2048;
        float proj[32];
#pragma unroll
        for (int m = 0; m < 32; ++m) proj[m] = 0.0f;
        for (int j = 0; j < 64; ++j) {
            float hgj = lds_h[j][tid] + fmaf(g0, Gw0[j], fmaf(g1, Gw1[j], Gbl[j]));
            const float* __restrict__ brow = Bl + (size_t)j * 32;
#pragma unroll
            for (int m = 0; m < 32; ++m)
                proj[m] = fmaf(hgj, brow[m], proj[m]);
        }

#pragma unroll
        for (int m = 0; m < 32; ++m) {
            float s = sin2pi(proj[m]);
            float c = cos2pi(proj[m]);
            const float* __restrict__ wsrow = Wout + (size_t)m * 16;
            const float* __restrict__ wcrow = Wout + (size_t)(m + 32) * 16;
#pragma unroll
            for (int o = 0; o < 16; ++o)
                outacc[o] = fmaf(s, wsrow[o], fmaf(c, wcrow[o], outacc[o]));
        }
    }

#pragma unroll
    for (int o = 0; o < 16; ++o)
        out[(size_t)n * 16 + o] = outacc[o] + bout[o];
}

extern "C" void kernel_launch(void* const* d_in, const int* in_sizes, int n_in,
                              void* d_out, int out_size, void* d_ws, size_t ws_size,
                              hipStream_t stream) {
    const float* input  = (const float*)d_in[0];
    const float* W0     = (const float*)d_in[1];
    const float* b0     = (const float*)d_in[2];
    const float* Ws     = (const float*)d_in[3];
    const float* bs     = (const float*)d_in[4];
    const float* tables = (const float*)d_in[5];
    const float* Gw     = (const float*)d_in[6];
    const float* Gb     = (const float*)d_in[7];
    const float* Bmat   = (const float*)d_in[8];
    const float* Wout   = (const float*)d_in[9];
    const float* bout   = (const float*)d_in[10];
    float* out = (float*)d_out;

    const int npts = in_sizes[0] / 3;

    // Replicate the reference's RES computation exactly (double precision).
    ResArr ra;
    const double growth = pow(512.0 / 16.0, 1.0 / (double)(N_LEVELS - 1));
    for (int i = 0; i < N_LEVELS; ++i)
        ra.r[i] = (float)floor(16.0 * pow(growth, (double)i));

    if (ws_size >= WS_NEEDED && (npts % 32) == 0) {
        const int NTOT = WSW_N + WSB_N + WSWO_N + WSP_N;   // 92928
        hipLaunchKernelGGL(prep_kernel, dim3((NTOT + 255) / 256), dim3(256), 0, stream,
                           Ws, Bmat, Wout, Gw, Gb, d_ws);
        hipLaunchKernelGGL(ffb_mfma, dim3(npts / 32), dim3(64), 0, stream,
                           input, W0, b0, bs, tables, bout, d_ws, out, npts, ra);
    } else {
        hipLaunchKernelGGL(ffb_valu, dim3((npts + BLK - 1) / BLK), dim3(BLK), 0, stream,
                           input, W0, b0, Ws, bs, tables, Gw, Gb, Bmat, Wout, bout,
                           out, npts, ra);
    }
}